// Round 13
// baseline (113.040 us; speedup 1.0000x reference)
//
#include <hip/hip_runtime.h>

// RecursiveNN — compact-K f16 MFMA, M=256 tiles, 8-wave blocks.
// z channel-last [b][y][x][48], feature order k=c*4+f (reference order) =>
// W1 fragment permutation identity. x0 channel-last f16 [256][256][16].
// R13: 512 threads / 8 waves per 16x16-px tile, ONE 32-row half per wave
// (vs R12's 4 waves x 2 halves). Weight hoist dropped (zero reuse at 1
// half/wave); __launch_bounds__(512,6) targets 24 waves/CU (R12 was 12,
// occupancy 27%, latency-bound). A-build row px built by threads 2px/2px+1
// = same wave as MFMA consumer -> still barrier-free.

namespace {
constexpr int NB = 16;
constexpr int ND = 12;
}

typedef __attribute__((ext_vector_type(8))) _Float16 f16x8;
typedef __attribute__((ext_vector_type(2))) __fp16  hf16x2;
typedef __attribute__((ext_vector_type(8))) short   s16x8;
typedef __attribute__((ext_vector_type(4))) short   s16x4;
typedef __attribute__((ext_vector_type(4))) float   f32x4;

__device__ __forceinline__ unsigned short f2h(float f) {
    return __builtin_bit_cast(unsigned short, (_Float16)f);   // RNE
}
__device__ __forceinline__ f16x8 splat8(float x) {
    _Float16 h = (_Float16)x;
    f16x8 v = {h,h,h,h,h,h,h,h};
    return v;
}
__device__ __forceinline__ f16x8 ld8(const unsigned short* p) {
    return __builtin_bit_cast(f16x8, *(const s16x8*)p);
}
__device__ __forceinline__ void st8(unsigned short* p, f16x8 v) {
    *(s16x8*)p = __builtin_bit_cast(s16x8, v);
}

__device__ __forceinline__ void up_taps(int y, int Hc, int& y0, int& y1, float& t1) {
    int j = y >> 1;
    if (y & 1) { y0 = j;            y1 = min(j+1, Hc-1); t1 = 0.25f; }
    else       { y0 = max(j-1, 0);  y1 = j;              t1 = 0.75f; }
}

// interleave 4 feature vectors (8ch each) into k=c*4+f chunk j (channels 2j,2j+1)
__device__ __forceinline__ s16x8 repack(f16x8 q0, f16x8 q1, f16x8 q2, f16x8 q3, int j) {
    s16x8 o;
#pragma unroll
    for (int t = 0; t < 8; ++t) {
        int cl = 2*j + (t >> 2);
        _Float16 vv = ((t&3)==0) ? q0[cl] : ((t&3)==1) ? q1[cl]
                    : ((t&3)==2) ? q2[cl] : q3[cl];
        o[t] = (short)__builtin_bit_cast(unsigned short, vv);
    }
    return o;
}

// ---------------- perceive body: x f32 planar -> z f16 [H][W][48] (k=c*4+f) -
template<int H, int W>
__device__ __forceinline__ void perceive_body(const float* __restrict__ x,
                                              unsigned short* __restrict__ z,
                                              int gid, int tid,
                                              unsigned short* S) {
    constexpr int HW = H*W;
    constexpr int TPX = W/16, BPI = (H/8)*TPX;
    const int b   = gid / BPI;
    const int rem = gid - b*BPI;
    const int tx  = (rem % TPX)*16, ty = (rem / TPX)*8;

#pragma unroll
    for (int i = 0; i < 12; ++i) {
        int e = i*256 + tid;
        if (e < 2880) {
            int c = e / 180, r = e - c*180;
            int ri = r / 18, ci = r - ri*18;
            int gy = (ty - 1 + ri) & (H-1);
            int gx = (tx - 1 + ci) & (W-1);
            unsigned short v = 0;
            if (c < 12) v = f2h(x[(b*ND + c)*HW + gy*W + gx]);
            S[r*16 + c] = v;
        }
    }
    __syncthreads();

    const int p = tid >> 1, h = tid & 1;
    const int py = p >> 4, px = p & 15;
    const unsigned short* Sc = &S[(py*18 + px)*16 + 8*h];
    f16x8 n00=ld8(Sc+0),   n01=ld8(Sc+16),  n02=ld8(Sc+32);
    f16x8 n10=ld8(Sc+288), n11=ld8(Sc+304), n12=ld8(Sc+320);
    f16x8 n20=ld8(Sc+576), n21=ld8(Sc+592), n22=ld8(Sc+608);
    f16x8 two = splat8(2.f), twelve = splat8(12.f);
    f16x8 sx  = (n02-n00) + two*(n12-n10) + (n22-n20);
    f16x8 sy  = (n20-n00) + two*(n21-n01) + (n22-n02);
    f16x8 lap = ((n00+n02)+(n20+n22)) + two*((n01+n10)+(n12+n21)) - twelve*n11;
    unsigned short* zp = z + ((size_t)(b*H + ty+py)*W + tx+px)*48 + 32*h;
    const int nchunk = 4 - 2*h;          // h=0: k 0..31 (4); h=1: k 32..47 (2)
#pragma unroll
    for (int j = 0; j < 4; ++j) {
        s16x8 o = repack(n11, sx, sy, lap, j);
        if (j < nchunk) *(s16x8*)(zp + 8*j) = o;
    }
}

// ---------------- merged prep kernel ----------------------------------------
__global__ __launch_bounds__(256)
void prep_kernel(const float* __restrict__ x0, const float* __restrict__ x1,
                 const float* __restrict__ x2,
                 const float* __restrict__ w01, const float* __restrict__ w11,
                 const float* __restrict__ w21,
                 const float* __restrict__ w02, const float* __restrict__ w12,
                 const float* __restrict__ w22,
                 unsigned short* __restrict__ x0cl,
                 unsigned short* __restrict__ z1h, unsigned short* __restrict__ z2h,
                 unsigned short* __restrict__ w1f0, unsigned short* __restrict__ w1f1,
                 unsigned short* __restrict__ w1f2,
                 unsigned short* __restrict__ w2h0, unsigned short* __restrict__ w2h1,
                 unsigned short* __restrict__ w2h2)
{
    __shared__ unsigned short S[2880];
    const int tid = threadIdx.x;
    const int bid = blockIdx.x;
    if (bid < 110) {
        int i = bid*256 + tid;
        if (i < 28032) {
            if (i < 9216) {                        // w1f0: [12kg][96][8]
                int kg = i / 768, rm = i - kg*768, n = rm >> 3, j = rm & 7;
                w1f0[i] = f2h(w01[n*96 + kg*8 + j]);
            } else if (i < 18432) {                // w1f1
                int e = i - 9216;
                int kg = e / 768, rm = e - kg*768, n = rm >> 3, j = rm & 7;
                w1f1[e] = f2h(w11[n*96 + kg*8 + j]);
            } else if (i < 24576) {                // w1f2: [8kg][96][8], K1=48
                int e = i - 18432;
                int kg = e / 768, rm = e - kg*768, n = rm >> 3, j = rm & 7;
                w1f2[e] = (kg < 6) ? f2h(w21[n*48 + kg*8 + j]) : (unsigned short)0;
            } else {                               // w2h x3: [12][96]
                int e = i - 24576;
                const float* w = (e < 1152) ? w02 : (e < 2304) ? w12 : w22;
                unsigned short* d = (e < 1152) ? w2h0 : (e < 2304) ? w2h1 : w2h2;
                int q = (e >= 2304) ? e-2304 : (e >= 1152) ? e-1152 : e;
                d[q] = f2h(w[q]);
            }
        }
    } else if (bid < 110 + 4096) {
        // cvtx: register-only repack, fully coalesced
        int pix = (bid-110)*256 + tid;             // [0, 16*65536)
        int b = pix >> 16, rem = pix & 65535;
        const float* xp = x0 + (size_t)b*ND*65536 + rem;
        s16x8 r0, r1;
#pragma unroll
        for (int c = 0; c < 8; ++c) r0[c] = (short)f2h(xp[c*65536]);
#pragma unroll
        for (int c = 0; c < 4; ++c) r1[c] = (short)f2h(xp[(8+c)*65536]);
#pragma unroll
        for (int c = 4; c < 8; ++c) r1[c] = 0;
        unsigned short* d = &x0cl[(size_t)pix*16];
        *(s16x8*)d       = r0;
        *(s16x8*)(d + 8) = r1;
    } else if (bid < 110 + 4096 + 2048) {
        perceive_body<128,128>(x1, z1h, bid - (110+4096), tid, S);
    } else {
        perceive_body<64,64>(x2, z2h, bid - (110+4096+2048), tid, S);
    }
}

// -------- fused per-resolution MFMA kernel (M=256 tile, 8 waves) ------------
template<int RES>
__global__ __launch_bounds__(512, 6)
void res_mfma(const unsigned short* __restrict__ xcl,
              const unsigned short* __restrict__ zown,
              const unsigned short* __restrict__ zc,
              const float* __restrict__ xres,
              const unsigned short* __restrict__ w1f,   // [NKG][96][8] f16
              const float* __restrict__ b1,
              const unsigned short* __restrict__ w2h,   // [12][96] f16
              float* __restrict__ out)
{
    constexpr int H  = (RES==0)?256:(RES==1)?128:64;
    constexpr int W  = H, Hc = H/2, Wc = W/2;
    constexpr int HW = H*W;
    constexpr int TPX = W/16, BPI = (H/16)*TPX;
    constexpr int NK  = (RES==2)?2:3;          // layer-1 k-steps (K=NK*32)

    __shared__ unsigned short Alds[12*256*8];  // [kg][row][8]; A then H (48KB)

    const int tid = threadIdx.x;
    const int cpx = gridDim.x >> 3;            // grid % 8 == 0 for all RES
    const int gid = (blockIdx.x & 7)*cpx + (blockIdx.x >> 3);
    const int b   = gid / BPI;
    const int rem = gid - b*BPI;
    const int tx  = (rem % TPX)*16, ty = (rem / TPX)*16;

    const int wid = tid >> 6, lane = tid & 63;
    const int fr  = lane & 15, g = lane >> 4;
    const int p   = tid >> 1, h = tid & 1;     // pixel-row + half (A-build)
    const int py  = p >> 4, px = p & 15;
    const int gy  = ty + py, gx = tx + px;

    // ================= build A (2 threads = 1 pixel; no barrier) ===========
    if (RES == 0) {
        int ym=(gy-1)&(H-1), yp=(gy+1)&(H-1);
        int xm=(gx-1)&(W-1), xq=(gx+1)&(W-1);
        const unsigned short* bp = xcl + (size_t)b*HW*16 + 8*h;
        f16x8 n00=ld8(&bp[(ym*W+xm)*16]), n01=ld8(&bp[(ym*W+gx)*16]), n02=ld8(&bp[(ym*W+xq)*16]);
        f16x8 n10=ld8(&bp[(gy*W+xm)*16]), n11=ld8(&bp[(gy*W+gx)*16]), n12=ld8(&bp[(gy*W+xq)*16]);
        f16x8 n20=ld8(&bp[(yp*W+xm)*16]), n21=ld8(&bp[(yp*W+gx)*16]), n22=ld8(&bp[(yp*W+xq)*16]);
        f16x8 two = splat8(2.f), twelve = splat8(12.f);
        f16x8 sx  = (n02-n00) + two*(n12-n10) + (n22-n20);
        f16x8 sy  = (n20-n00) + two*(n21-n01) + (n22-n02);
        f16x8 lap = ((n00+n02)+(n20+n22)) + two*((n01+n10)+(n12+n21)) - twelve*n11;
        const int jn = h ? 2 : 4;              // kg = 4h + j
#pragma unroll
        for (int j = 0; j < 4; ++j) {
            s16x8 o = repack(n11, sx, sy, lap, j);
            if (j < jn) *(s16x8*)&Alds[(4*h + j)*2048 + p*8] = o;
        }
    } else {
        const unsigned short* src = &zown[((size_t)(b*H + gy)*W + gx)*48 + 24*h];
#pragma unroll
        for (int j = 0; j < 3; ++j)
            *(s16x8*)&Alds[(3*h + j)*2048 + p*8] = *(const s16x8*)&src[8*j];
        if (RES == 2) {
            s16x8 zz = {0,0,0,0,0,0,0,0};
            *(s16x8*)&Alds[(6 + h)*2048 + p*8] = zz;
        }
    }

    if (RES != 2) {
        // bilinear 2x upsample of coarse z (48ch): half-thread does 3 chunks
        int ys0, ys1, xs0, xs1; float tyw, txw;
        up_taps(gy, Hc, ys0, ys1, tyw);
        up_taps(gx, Wc, xs0, xs1, txw);
        float wy0 = 1.f - tyw, wx0 = 1.f - txw;
        f16x8 w00 = splat8(wy0*wx0), w01v = splat8(wy0*txw);
        f16x8 w10 = splat8(tyw*wx0), w11v = splat8(tyw*txw);
        const int o00 = ((b*Hc + ys0)*Wc + xs0)*48 + 24*h;
        const int o01 = ((b*Hc + ys0)*Wc + xs1)*48 + 24*h;
        const int o10 = ((b*Hc + ys1)*Wc + xs0)*48 + 24*h;
        const int o11 = ((b*Hc + ys1)*Wc + xs1)*48 + 24*h;
#pragma unroll
        for (int j = 0; j < 3; ++j) {
            f16x8 t00 = ld8(&zc[o00 + 8*j]);
            f16x8 t01 = ld8(&zc[o01 + 8*j]);
            f16x8 t10 = ld8(&zc[o10 + 8*j]);
            f16x8 t11 = ld8(&zc[o11 + 8*j]);
            f16x8 v = t00*w00 + t01*w01v + t10*w10 + t11*w11v;
            st8(&Alds[(6 + 3*h + j)*2048 + p*8], v);
        }
    }

    // ====== layer 1 MFMA (one 32-row half per wave), swapped: D=[o][px] =====
    const int rbase = wid*32;
    f32x4 acc[2][6] = {};
#pragma unroll
    for (int ks = 0; ks < NK; ++ks) {
        const int kgo = (ks*4 + g)*2048;
        f16x8 a0 = ld8(&Alds[kgo + (rbase +      fr)*8]);
        f16x8 a1 = ld8(&Alds[kgo + (rbase + 16 + fr)*8]);
#pragma unroll
        for (int nt = 0; nt < 6; ++nt) {
            f16x8 bb = ld8(&w1f[((ks*4 + g)*96 + nt*16 + fr)*8]);
            acc[0][nt] = __builtin_amdgcn_mfma_f32_16x16x32_f16(bb, a0, acc[0][nt], 0, 0, 0);
            acc[1][nt] = __builtin_amdgcn_mfma_f32_16x16x32_f16(bb, a1, acc[1][nt], 0, 0, 0);
        }
    }

    // ====== bias + relu -> H, packed b64 writes (own-wave rows) ======
#pragma unroll
    for (int nt = 0; nt < 6; ++nt) {
        const float4 bv4 = *(const float4*)&b1[nt*16 + g*4];
#pragma unroll
        for (int pt = 0; pt < 2; ++pt) {
            float h0 = fmaxf(acc[pt][nt][0] + bv4.x, 0.f);
            float h1 = fmaxf(acc[pt][nt][1] + bv4.y, 0.f);
            float h2f_ = fmaxf(acc[pt][nt][2] + bv4.z, 0.f);
            float h3 = fmaxf(acc[pt][nt][3] + bv4.w, 0.f);
            hf16x2 lo = __builtin_amdgcn_cvt_pkrtz(h0, h1);
            hf16x2 hi = __builtin_amdgcn_cvt_pkrtz(h2f_, h3);
            uint2 qq;
            qq.x = __builtin_bit_cast(unsigned int, lo);
            qq.y = __builtin_bit_cast(unsigned int, hi);
            int row = rbase + pt*16 + fr;
            *(s16x4*)&Alds[(nt*2 + (g>>1))*2048 + row*8 + (g&1)*4] =
                __builtin_bit_cast(s16x4, qq);
        }
    }

    // ================= layer 2 MFMA (K=96, N=16 padded) =================
    f32x4 acc2[2] = {};
#pragma unroll
    for (int ks = 0; ks < 3; ++ks) {
        const int kgo = (ks*4 + g)*2048;
        s16x8 wv = {0,0,0,0,0,0,0,0};
        if (fr < 12) wv = *(const s16x8*)&w2h[fr*96 + ks*32 + g*8];
        f16x8 w2frag = __builtin_bit_cast(f16x8, wv);
#pragma unroll
        for (int m = 0; m < 2; ++m) {
            f16x8 ah = ld8(&Alds[kgo + (rbase + m*16 + fr)*8]);
            acc2[m] = __builtin_amdgcn_mfma_f32_16x16x32_f16(ah, w2frag, acc2[m], 0, 0, 0);
        }
    }

    // ================= store =================
    if (fr < 12) {
        const int chbase = (b*ND + fr)*HW;
#pragma unroll
        for (int m = 0; m < 2; ++m) {
            int oy = ty + 2*wid + m;
            int ox = tx + g*4;
            float4 vv;
            vv.x = acc2[m][0]; vv.y = acc2[m][1];
            vv.z = acc2[m][2]; vv.w = acc2[m][3];
            if (RES == 2) {
                const float4 rr = *(const float4*)&xres[chbase + oy*W + ox];
                vv.x += rr.x; vv.y += rr.y; vv.z += rr.z; vv.w += rr.w;
            }
            *(float4*)&out[chbase + oy*W + ox] = vv;
        }
    }
}

extern "C" void kernel_launch(void* const* d_in, const int* in_sizes, int n_in,
                              void* d_out, int out_size, void* d_ws, size_t ws_size,
                              hipStream_t stream) {
    const float* x0   = (const float*)d_in[0];
    const float* x1   = (const float*)d_in[1];
    const float* x2   = (const float*)d_in[2];
    const float* w0_1 = (const float*)d_in[3];
    const float* b0_1 = (const float*)d_in[4];
    const float* w0_2 = (const float*)d_in[5];
    const float* w1_1 = (const float*)d_in[6];
    const float* b1_1 = (const float*)d_in[7];
    const float* w1_2 = (const float*)d_in[8];
    const float* w2_1 = (const float*)d_in[9];
    const float* b2_1 = (const float*)d_in[10];
    const float* w2_2 = (const float*)d_in[11];
    float* out = (float*)d_out;

    unsigned short* z1h  = (unsigned short*)d_ws;       // [16][128][128][48]
    unsigned short* z2h  = z1h + 16*128*128*48;         // [16][64][64][48]
    unsigned short* w1f0 = z2h + 16*64*64*48;           // [12][96][8]
    unsigned short* w1f1 = w1f0 + 9216;                 // [12][96][8]
    unsigned short* w1f2 = w1f1 + 9216;                 // [8][96][8]
    unsigned short* w2h0 = w1f2 + 6144;                 // [12][96]
    unsigned short* w2h1 = w2h0 + 1152;
    unsigned short* w2h2 = w2h1 + 1152;
    unsigned short* x0cl = w2h2 + 1152;                 // [16][256][256][16]

    prep_kernel<<<6766, 256, 0, stream>>>(x0, x1, x2,
                                          w0_1, w1_1, w2_1, w0_2, w1_2, w2_2,
                                          x0cl, z1h, z2h,
                                          w1f0, w1f1, w1f2, w2h0, w2h1, w2h2);

    res_mfma<0><<<NB*256, 512, 0, stream>>>(x0cl, nullptr, z1h, nullptr,
                                            w1f0, b0_1, w2h0, out);
    res_mfma<1><<<NB*64,  512, 0, stream>>>(nullptr, z1h, z2h, nullptr,
                                            w1f1, b1_1, w2h1,
                                            out + NB*ND*256*256);
    res_mfma<2><<<NB*16,  512, 0, stream>>>(nullptr, z2h, nullptr, x2,
                                            w1f2, b2_1, w2h2,
                                            out + NB*ND*256*256 + NB*ND*128*128);
}

// Round 14
// 91.510 us; speedup vs baseline: 1.2353x; 1.2353x over previous
//
#include <hip/hip_runtime.h>

// RecursiveNN — compact-K f16 MFMA, M=256 tiles, register-hoisted weights.
// R14: revert to R12's res structure (4 waves x 2 halves, weight hoist —
// R13 proved occupancy beyond ~12 waves/CU doesn't pay but weight traffic
// does), and FUSE res0/res1/res2 into one kernel (grid concat 4096+1024+256)
// so res1/res2 backfill the machine during res0's tail instead of running
// as two mostly-idle serialized dispatches (~13us of the 100.1).

namespace {
constexpr int NB = 16;
constexpr int ND = 12;
}

typedef __attribute__((ext_vector_type(8))) _Float16 f16x8;
typedef __attribute__((ext_vector_type(2))) __fp16  hf16x2;
typedef __attribute__((ext_vector_type(8))) short   s16x8;
typedef __attribute__((ext_vector_type(4))) short   s16x4;
typedef __attribute__((ext_vector_type(4))) float   f32x4;

__device__ __forceinline__ unsigned short f2h(float f) {
    return __builtin_bit_cast(unsigned short, (_Float16)f);   // RNE
}
__device__ __forceinline__ f16x8 splat8(float x) {
    _Float16 h = (_Float16)x;
    f16x8 v = {h,h,h,h,h,h,h,h};
    return v;
}
__device__ __forceinline__ f16x8 ld8(const unsigned short* p) {
    return __builtin_bit_cast(f16x8, *(const s16x8*)p);
}
__device__ __forceinline__ void st8(unsigned short* p, f16x8 v) {
    *(s16x8*)p = __builtin_bit_cast(s16x8, v);
}

__device__ __forceinline__ void up_taps(int y, int Hc, int& y0, int& y1, float& t1) {
    int j = y >> 1;
    if (y & 1) { y0 = j;            y1 = min(j+1, Hc-1); t1 = 0.25f; }
    else       { y0 = max(j-1, 0);  y1 = j;              t1 = 0.75f; }
}

// interleave 4 feature vectors (8ch each) into k=c*4+f chunk j (channels 2j,2j+1)
__device__ __forceinline__ s16x8 repack(f16x8 q0, f16x8 q1, f16x8 q2, f16x8 q3, int j) {
    s16x8 o;
#pragma unroll
    for (int t = 0; t < 8; ++t) {
        int cl = 2*j + (t >> 2);
        _Float16 vv = ((t&3)==0) ? q0[cl] : ((t&3)==1) ? q1[cl]
                    : ((t&3)==2) ? q2[cl] : q3[cl];
        o[t] = (short)__builtin_bit_cast(unsigned short, vv);
    }
    return o;
}

// ---------------- perceive body: x f32 planar -> z f16 [H][W][48] (k=c*4+f) -
template<int H, int W>
__device__ __forceinline__ void perceive_body(const float* __restrict__ x,
                                              unsigned short* __restrict__ z,
                                              int gid, int tid,
                                              unsigned short* S) {
    constexpr int HW = H*W;
    constexpr int TPX = W/16, BPI = (H/8)*TPX;
    const int b   = gid / BPI;
    const int rem = gid - b*BPI;
    const int tx  = (rem % TPX)*16, ty = (rem / TPX)*8;

#pragma unroll
    for (int i = 0; i < 12; ++i) {
        int e = i*256 + tid;
        if (e < 2880) {
            int c = e / 180, r = e - c*180;
            int ri = r / 18, ci = r - ri*18;
            int gy = (ty - 1 + ri) & (H-1);
            int gx = (tx - 1 + ci) & (W-1);
            unsigned short v = 0;
            if (c < 12) v = f2h(x[(b*ND + c)*HW + gy*W + gx]);
            S[r*16 + c] = v;
        }
    }
    __syncthreads();

    const int p = tid >> 1, h = tid & 1;
    const int py = p >> 4, px = p & 15;
    const unsigned short* Sc = &S[(py*18 + px)*16 + 8*h];
    f16x8 n00=ld8(Sc+0),   n01=ld8(Sc+16),  n02=ld8(Sc+32);
    f16x8 n10=ld8(Sc+288), n11=ld8(Sc+304), n12=ld8(Sc+320);
    f16x8 n20=ld8(Sc+576), n21=ld8(Sc+592), n22=ld8(Sc+608);
    f16x8 two = splat8(2.f), twelve = splat8(12.f);
    f16x8 sx  = (n02-n00) + two*(n12-n10) + (n22-n20);
    f16x8 sy  = (n20-n00) + two*(n21-n01) + (n22-n02);
    f16x8 lap = ((n00+n02)+(n20+n22)) + two*((n01+n10)+(n12+n21)) - twelve*n11;
    unsigned short* zp = z + ((size_t)(b*H + ty+py)*W + tx+px)*48 + 32*h;
    const int nchunk = 4 - 2*h;          // h=0: k 0..31 (4); h=1: k 32..47 (2)
#pragma unroll
    for (int j = 0; j < 4; ++j) {
        s16x8 o = repack(n11, sx, sy, lap, j);
        if (j < nchunk) *(s16x8*)(zp + 8*j) = o;
    }
}

// ---------------- merged prep kernel ----------------------------------------
__global__ __launch_bounds__(256)
void prep_kernel(const float* __restrict__ x0, const float* __restrict__ x1,
                 const float* __restrict__ x2,
                 const float* __restrict__ w01, const float* __restrict__ w11,
                 const float* __restrict__ w21,
                 const float* __restrict__ w02, const float* __restrict__ w12,
                 const float* __restrict__ w22,
                 unsigned short* __restrict__ x0cl,
                 unsigned short* __restrict__ z1h, unsigned short* __restrict__ z2h,
                 unsigned short* __restrict__ w1f0, unsigned short* __restrict__ w1f1,
                 unsigned short* __restrict__ w1f2,
                 unsigned short* __restrict__ w2h0, unsigned short* __restrict__ w2h1,
                 unsigned short* __restrict__ w2h2)
{
    __shared__ unsigned short S[2880];
    const int tid = threadIdx.x;
    const int bid = blockIdx.x;
    if (bid < 110) {
        int i = bid*256 + tid;
        if (i < 28032) {
            if (i < 9216) {                        // w1f0: [12kg][96][8]
                int kg = i / 768, rm = i - kg*768, n = rm >> 3, j = rm & 7;
                w1f0[i] = f2h(w01[n*96 + kg*8 + j]);
            } else if (i < 18432) {                // w1f1
                int e = i - 9216;
                int kg = e / 768, rm = e - kg*768, n = rm >> 3, j = rm & 7;
                w1f1[e] = f2h(w11[n*96 + kg*8 + j]);
            } else if (i < 24576) {                // w1f2: [8kg][96][8], K1=48
                int e = i - 18432;
                int kg = e / 768, rm = e - kg*768, n = rm >> 3, j = rm & 7;
                w1f2[e] = (kg < 6) ? f2h(w21[n*48 + kg*8 + j]) : (unsigned short)0;
            } else {                               // w2h x3: [12][96]
                int e = i - 24576;
                const float* w = (e < 1152) ? w02 : (e < 2304) ? w12 : w22;
                unsigned short* d = (e < 1152) ? w2h0 : (e < 2304) ? w2h1 : w2h2;
                int q = (e >= 2304) ? e-2304 : (e >= 1152) ? e-1152 : e;
                d[q] = f2h(w[q]);
            }
        }
    } else if (bid < 110 + 4096) {
        // cvtx: register-only repack, fully coalesced
        int pix = (bid-110)*256 + tid;             // [0, 16*65536)
        int b = pix >> 16, rem = pix & 65535;
        const float* xp = x0 + (size_t)b*ND*65536 + rem;
        s16x8 r0, r1;
#pragma unroll
        for (int c = 0; c < 8; ++c) r0[c] = (short)f2h(xp[c*65536]);
#pragma unroll
        for (int c = 0; c < 4; ++c) r1[c] = (short)f2h(xp[(8+c)*65536]);
#pragma unroll
        for (int c = 4; c < 8; ++c) r1[c] = 0;
        unsigned short* d = &x0cl[(size_t)pix*16];
        *(s16x8*)d       = r0;
        *(s16x8*)(d + 8) = r1;
    } else if (bid < 110 + 4096 + 2048) {
        perceive_body<128,128>(x1, z1h, bid - (110+4096), tid, S);
    } else {
        perceive_body<64,64>(x2, z2h, bid - (110+4096+2048), tid, S);
    }
}

// -------- per-resolution MFMA body (M=256 tile, 4 waves x 2 halves) ---------
template<int RES>
__device__ __forceinline__
void res_body(const unsigned short* __restrict__ xcl,
              const unsigned short* __restrict__ zown,
              const unsigned short* __restrict__ zc,
              const float* __restrict__ xres,
              const unsigned short* __restrict__ w1f,   // [NKG][96][8] f16
              const float* __restrict__ b1,
              const unsigned short* __restrict__ w2h,   // [12][96] f16
              float* __restrict__ out,
              int bid, int tid, unsigned short* Alds)
{
    constexpr int H  = (RES==0)?256:(RES==1)?128:64;
    constexpr int W  = H, Hc = H/2, Wc = W/2;
    constexpr int HW = H*W;
    constexpr int TPX = W/16, BPI = (H/16)*TPX;
    constexpr int NBLK = NB*BPI;               // segment size (const, %8==0)
    constexpr int NK  = (RES==2)?2:3;          // layer-1 k-steps (K=NK*32)

    constexpr int cpx = NBLK >> 3;             // XCD swizzle within segment
    const int gid = (bid & 7)*cpx + (bid >> 3);
    const int b   = gid / BPI;
    const int rem = gid - b*BPI;
    const int tx  = (rem % TPX)*16, ty = (rem / TPX)*16;

    const int wid = tid >> 6, lane = tid & 63;
    const int fr  = lane & 15, g = lane >> 4;
    const int r   = tid;                       // pixel-row 0..255 (own-wave)
    const int py  = r >> 4, px = r & 15;
    const int gy  = ty + py, gx = tx + px;

    // ================= build A (1 thread = 1 pixel; no barrier) ============
    if (RES == 0) {
        int ym=(gy-1)&(H-1), yp=(gy+1)&(H-1);
        int xm=(gx-1)&(W-1), xq=(gx+1)&(W-1);
        const unsigned short* bp = xcl + (size_t)b*HW*16;
        const int r00=(ym*W+xm)*16, r01=(ym*W+gx)*16, r02=(ym*W+xq)*16;
        const int r10=(gy*W+xm)*16, r11=(gy*W+gx)*16, r12=(gy*W+xq)*16;
        const int r20=(yp*W+xm)*16, r21=(yp*W+gx)*16, r22=(yp*W+xq)*16;
#pragma unroll
        for (int grp = 0; grp < 2; ++grp) {
            const int off = grp*8;
            f16x8 n00=ld8(&bp[r00+off]), n01=ld8(&bp[r01+off]), n02=ld8(&bp[r02+off]);
            f16x8 n10=ld8(&bp[r10+off]), n11=ld8(&bp[r11+off]), n12=ld8(&bp[r12+off]);
            f16x8 n20=ld8(&bp[r20+off]), n21=ld8(&bp[r21+off]), n22=ld8(&bp[r22+off]);
            f16x8 two = splat8(2.f), twelve = splat8(12.f);
            f16x8 sx  = (n02-n00) + two*(n12-n10) + (n22-n20);
            f16x8 sy  = (n20-n00) + two*(n21-n01) + (n22-n02);
            f16x8 lap = ((n00+n02)+(n20+n22)) + two*((n01+n10)+(n12+n21)) - twelve*n11;
            const int jn = grp ? 2 : 4;        // grp1: only ch 8..11 valid
#pragma unroll
            for (int j = 0; j < 4; ++j) {
                s16x8 o = repack(n11, sx, sy, lap, j);
                if (j < jn) *(s16x8*)&Alds[(grp*4 + j)*2048 + r*8] = o;
            }
        }
    } else {
        const unsigned short* src = &zown[((size_t)(b*H + gy)*W + gx)*48];
#pragma unroll
        for (int j = 0; j < 6; ++j)
            *(s16x8*)&Alds[j*2048 + r*8] = *(const s16x8*)&src[8*j];
        if (RES == 2) {
            s16x8 zz = {0,0,0,0,0,0,0,0};
            *(s16x8*)&Alds[6*2048 + r*8] = zz;
            *(s16x8*)&Alds[7*2048 + r*8] = zz;
        }
    }

    if (RES != 2) {
        // bilinear 2x upsample of coarse z (48ch) -> kg 6..11
        int ys0, ys1, xs0, xs1; float tyw, txw;
        up_taps(gy, Hc, ys0, ys1, tyw);
        up_taps(gx, Wc, xs0, xs1, txw);
        float wy0 = 1.f - tyw, wx0 = 1.f - txw;
        f16x8 w00 = splat8(wy0*wx0), w01v = splat8(wy0*txw);
        f16x8 w10 = splat8(tyw*wx0), w11v = splat8(tyw*txw);
        const int o00 = ((b*Hc + ys0)*Wc + xs0)*48;
        const int o01 = ((b*Hc + ys0)*Wc + xs1)*48;
        const int o10 = ((b*Hc + ys1)*Wc + xs0)*48;
        const int o11 = ((b*Hc + ys1)*Wc + xs1)*48;
#pragma unroll
        for (int j = 0; j < 6; ++j) {
            f16x8 t00 = ld8(&zc[o00 + 8*j]);
            f16x8 t01 = ld8(&zc[o01 + 8*j]);
            f16x8 t10 = ld8(&zc[o10 + 8*j]);
            f16x8 t11 = ld8(&zc[o11 + 8*j]);
            f16x8 v = t00*w00 + t01*w01v + t10*w10 + t11*w11v;
            st8(&Alds[(6 + j)*2048 + r*8], v);
        }
    }

    // ====== hoist W fragments to registers (once per wave, after A-build) ===
    f16x8 w1r[3][6];
#pragma unroll
    for (int ks = 0; ks < NK; ++ks)
#pragma unroll
        for (int nt = 0; nt < 6; ++nt)
            w1r[ks][nt] = ld8(&w1f[((ks*4 + g)*96 + nt*16 + fr)*8]);
    f16x8 w2r[3];
#pragma unroll
    for (int ks = 0; ks < 3; ++ks) {
        s16x8 v = {0,0,0,0,0,0,0,0};
        if (fr < 12) v = *(const s16x8*)&w2h[fr*96 + ks*32 + g*8];
        w2r[ks] = __builtin_bit_cast(f16x8, v);
    }

    // ====== two 32-row halves per wave (M=64/wave), reusing W regs ==========
#pragma unroll 1
    for (int h2 = 0; h2 < 2; ++h2) {
        const int rbase = wid*64 + h2*32;

        // layer 1 MFMA, swapped: D = [o][pixel]
        f32x4 acc[2][6] = {};
#pragma unroll
        for (int ks = 0; ks < NK; ++ks) {
            const int kgo = (ks*4 + g)*2048;
            f16x8 a0 = ld8(&Alds[kgo + (rbase +      fr)*8]);
            f16x8 a1 = ld8(&Alds[kgo + (rbase + 16 + fr)*8]);
#pragma unroll
            for (int nt = 0; nt < 6; ++nt) {
                acc[0][nt] = __builtin_amdgcn_mfma_f32_16x16x32_f16(w1r[ks][nt], a0, acc[0][nt], 0, 0, 0);
                acc[1][nt] = __builtin_amdgcn_mfma_f32_16x16x32_f16(w1r[ks][nt], a1, acc[1][nt], 0, 0, 0);
            }
        }

        // bias + relu -> H, packed b64 writes (own-wave rows)
#pragma unroll
        for (int nt = 0; nt < 6; ++nt) {
            const float4 bv4 = *(const float4*)&b1[nt*16 + g*4];
#pragma unroll
            for (int pt = 0; pt < 2; ++pt) {
                float h0 = fmaxf(acc[pt][nt][0] + bv4.x, 0.f);
                float h1 = fmaxf(acc[pt][nt][1] + bv4.y, 0.f);
                float h2f_ = fmaxf(acc[pt][nt][2] + bv4.z, 0.f);
                float h3 = fmaxf(acc[pt][nt][3] + bv4.w, 0.f);
                hf16x2 lo = __builtin_amdgcn_cvt_pkrtz(h0, h1);
                hf16x2 hi = __builtin_amdgcn_cvt_pkrtz(h2f_, h3);
                uint2 qq;
                qq.x = __builtin_bit_cast(unsigned int, lo);
                qq.y = __builtin_bit_cast(unsigned int, hi);
                int row = rbase + pt*16 + fr;
                *(s16x4*)&Alds[(nt*2 + (g>>1))*2048 + row*8 + (g&1)*4] =
                    __builtin_bit_cast(s16x4, qq);
            }
        }

        // layer 2 MFMA (K=96, N=16 padded)
        f32x4 acc2[2] = {};
#pragma unroll
        for (int ks = 0; ks < 3; ++ks) {
            const int kgo = (ks*4 + g)*2048;
#pragma unroll
            for (int m = 0; m < 2; ++m) {
                f16x8 ah = ld8(&Alds[kgo + (rbase + m*16 + fr)*8]);
                acc2[m] = __builtin_amdgcn_mfma_f32_16x16x32_f16(ah, w2r[ks], acc2[m], 0, 0, 0);
            }
        }

        // store
        if (fr < 12) {
            const int chbase = (b*ND + fr)*HW;
#pragma unroll
            for (int m = 0; m < 2; ++m) {
                int oy = ty + 4*wid + 2*h2 + m;
                int ox = tx + g*4;
                float4 vv;
                vv.x = acc2[m][0]; vv.y = acc2[m][1];
                vv.z = acc2[m][2]; vv.w = acc2[m][3];
                if (RES == 2) {
                    const float4 rr = *(const float4*)&xres[chbase + oy*W + ox];
                    vv.x += rr.x; vv.y += rr.y; vv.z += rr.z; vv.w += rr.w;
                }
                *(float4*)&out[chbase + oy*W + ox] = vv;
            }
        }
    }
}

// -------- fused res kernel: grid = 4096 (res0) + 1024 (res1) + 256 (res2) ---
__global__ __launch_bounds__(256, 3)
void fused_res(const unsigned short* __restrict__ x0cl,
               const unsigned short* __restrict__ z1h,
               const unsigned short* __restrict__ z2h,
               const float* __restrict__ x2,
               const unsigned short* __restrict__ w1f0,
               const unsigned short* __restrict__ w1f1,
               const unsigned short* __restrict__ w1f2,
               const float* __restrict__ b0_1, const float* __restrict__ b1_1,
               const float* __restrict__ b2_1,
               const unsigned short* __restrict__ w2h0,
               const unsigned short* __restrict__ w2h1,
               const unsigned short* __restrict__ w2h2,
               float* __restrict__ out)
{
    __shared__ unsigned short Alds[12*256*8];  // 48KB, shared by all branches
    const int tid = threadIdx.x;
    const int bid = blockIdx.x;
    float* out1 = out + NB*ND*256*256;
    float* out2 = out1 + NB*ND*128*128;
    if (bid < 4096) {
        res_body<0>(x0cl, nullptr, z1h, nullptr, w1f0, b0_1, w2h0, out,
                    bid, tid, Alds);
    } else if (bid < 4096 + 1024) {
        res_body<1>(nullptr, z1h, z2h, nullptr, w1f1, b1_1, w2h1, out1,
                    bid - 4096, tid, Alds);
    } else {
        res_body<2>(nullptr, z2h, nullptr, x2, w1f2, b2_1, w2h2, out2,
                    bid - (4096 + 1024), tid, Alds);
    }
}

extern "C" void kernel_launch(void* const* d_in, const int* in_sizes, int n_in,
                              void* d_out, int out_size, void* d_ws, size_t ws_size,
                              hipStream_t stream) {
    const float* x0   = (const float*)d_in[0];
    const float* x1   = (const float*)d_in[1];
    const float* x2   = (const float*)d_in[2];
    const float* w0_1 = (const float*)d_in[3];
    const float* b0_1 = (const float*)d_in[4];
    const float* w0_2 = (const float*)d_in[5];
    const float* w1_1 = (const float*)d_in[6];
    const float* b1_1 = (const float*)d_in[7];
    const float* w1_2 = (const float*)d_in[8];
    const float* w2_1 = (const float*)d_in[9];
    const float* b2_1 = (const float*)d_in[10];
    const float* w2_2 = (const float*)d_in[11];
    float* out = (float*)d_out;

    unsigned short* z1h  = (unsigned short*)d_ws;       // [16][128][128][48]
    unsigned short* z2h  = z1h + 16*128*128*48;         // [16][64][64][48]
    unsigned short* w1f0 = z2h + 16*64*64*48;           // [12][96][8]
    unsigned short* w1f1 = w1f0 + 9216;                 // [12][96][8]
    unsigned short* w1f2 = w1f1 + 9216;                 // [8][96][8]
    unsigned short* w2h0 = w1f2 + 6144;                 // [12][96]
    unsigned short* w2h1 = w2h0 + 1152;
    unsigned short* w2h2 = w2h1 + 1152;
    unsigned short* x0cl = w2h2 + 1152;                 // [16][256][256][16]

    prep_kernel<<<6766, 256, 0, stream>>>(x0, x1, x2,
                                          w0_1, w1_1, w2_1, w0_2, w1_2, w2_2,
                                          x0cl, z1h, z2h,
                                          w1f0, w1f1, w1f2, w2h0, w2h1, w2h2);

    fused_res<<<4096 + 1024 + 256, 256, 0, stream>>>(
        x0cl, z1h, z2h, x2,
        w1f0, w1f1, w1f2,
        b0_1, b1_1, b2_1,
        w2h0, w2h1, w2h2, out);
}